// Round 1
// baseline (141.327 us; speedup 1.0000x reference)
//
#include <hip/hip_runtime.h>

#define TLEN 512
#define KLEN 11
#define XPAD_L 256
#define XPAD_TOTAL 1664  // covers read index range [1, 1617] with zeros outside x

__global__ __launch_bounds__(256) void rf_kernel(
    const float* __restrict__ x, const float* __restrict__ weight,
    const float* __restrict__ bias, const int* __restrict__ dilation,
    const int* __restrict__ padding, const int* __restrict__ out_len,
    float* __restrict__ out, int K)
{
    __shared__ float xs[XPAD_TOTAL];
    const int t = threadIdx.x;
    const int b = blockIdx.y;
    const int kbase = blockIdx.x * 4;

    // Zero the padded buffer, then overlay x[b,:]. Each LDS slot is zeroed and
    // (possibly) filled by the SAME thread, so one barrier at the end suffices.
    for (int i = t; i < XPAD_TOTAL; i += 256) xs[i] = 0.0f;
    xs[XPAD_L + t]        = x[b * TLEN + t];
    xs[XPAD_L + 256 + t]  = x[b * TLEN + 256 + t];
    __syncthreads();

    const int wave = t >> 6;
    const int lane = t & 63;
    const int k = kbase + wave;

    const int dil  = dilation[k];
    const int pad  = padding[k];
    const int olen = out_len[k];
    const float bs = bias[k];
    const float* wk = weight + k * KLEN;

    float acc[8];
    #pragma unroll
    for (int i = 0; i < 8; ++i) acc[i] = 0.0f;

    #pragma unroll
    for (int j = 0; j < KLEN; ++j) {
        const float wj = wk[j];
        const int s = XPAD_L + lane + j * dil - pad;   // zero-padded: no bounds check
        #pragma unroll
        for (int i = 0; i < 8; ++i) {
            acc[i] = fmaf(wj, xs[s + 64 * i], acc[i]);
        }
    }

    float mx = -INFINITY;
    int cnt = 0;
    #pragma unroll
    for (int i = 0; i < 8; ++i) {
        const int p = lane + 64 * i;
        const float conv = acc[i] + bs;
        if (p < olen) {
            mx = fmaxf(mx, conv);
            cnt += (conv > 0.0f) ? 1 : 0;
        }
    }

    // wave64 butterfly reduction
    #pragma unroll
    for (int off = 32; off > 0; off >>= 1) {
        mx = fmaxf(mx, __shfl_xor(mx, off, 64));
        cnt += __shfl_xor(cnt, off, 64);
    }

    if (lane == 0) {
        float* o = out + (size_t)b * (2 * K) + 2 * k;
        o[0] = mx;
        o[1] = (float)cnt / (float)olen;
    }
}

extern "C" void kernel_launch(void* const* d_in, const int* in_sizes, int n_in,
                              void* d_out, int out_size, void* d_ws, size_t ws_size,
                              hipStream_t stream) {
    const float* x    = (const float*)d_in[0];
    const float* w    = (const float*)d_in[1];
    const float* bias = (const float*)d_in[2];
    const int* dil    = (const int*)d_in[3];
    const int* pad    = (const int*)d_in[4];
    const int* olen   = (const int*)d_in[5];
    float* out        = (float*)d_out;

    const int K = in_sizes[2];          // bias has K elements (4096)
    const int B = in_sizes[0] / TLEN;   // 32

    dim3 grid(K / 4, B);
    rf_kernel<<<grid, 256, 0, stream>>>(x, w, bias, dil, pad, olen, out, K);
}